// Round 4
// baseline (366.068 us; speedup 1.0000x reference)
//
#include <hip/hip_runtime.h>
#include <hip/hip_bf16.h>
#include <cstdint>
#include <cstddef>

// Problem constants (B=1 implicit)
static constexpr int kT   = 1024;
static constexpr int kCV  = 8;
static constexpr int kDim = 2048;
static constexpr int kNH  = 32;
static constexpr int kHD  = 64;
static constexpr int kW   = 8;
static constexpr int kK   = 2048;   // inner dim of every GEMM

using bf16_t = __hip_bfloat16;

typedef __attribute__((ext_vector_type(8))) __bf16 bf16x8;
typedef __attribute__((ext_vector_type(4))) float  f32x4;

__device__ __forceinline__ float bf_bits_to_f32(unsigned short u) {
    union { unsigned int i; float f; } c;
    c.i = ((unsigned int)u) << 16;
    return c.f;
}

// ---------------------------------------------------------------------------
// Merged fp32 -> bf16 cast for all 6 inputs in ONE launch.
// ---------------------------------------------------------------------------
struct CastArgs {
    const float* src[6];
    bf16_t*      dst[6];
    int          cum[7];   // cumulative 8-elem chunk counts
};

__global__ void cast_all(CastArgs a, int total_chunks) {
    const int c = blockIdx.x * blockDim.x + threadIdx.x;
    if (c >= total_chunks) return;
    int r = 0;
#pragma unroll
    for (int i = 1; i <= 5; ++i) r += (c >= a.cum[i]) ? 1 : 0;
    const int local = c - a.cum[r];
    const float* s = a.src[r] + (size_t)local * 8;
    bf16_t*      d = a.dst[r] + (size_t)local * 8;
    const float4 lo = *reinterpret_cast<const float4*>(s);
    const float4 hi = *reinterpret_cast<const float4*>(s + 4);
    union { bf16_t h[8]; uint4 u; } o;
    o.h[0] = __float2bfloat16(lo.x); o.h[1] = __float2bfloat16(lo.y);
    o.h[2] = __float2bfloat16(lo.z); o.h[3] = __float2bfloat16(lo.w);
    o.h[4] = __float2bfloat16(hi.x); o.h[5] = __float2bfloat16(hi.y);
    o.h[6] = __float2bfloat16(hi.z); o.h[7] = __float2bfloat16(hi.w);
    *reinterpret_cast<uint4*>(d) = o.u;
}

// ---------------------------------------------------------------------------
// GEMM body: C[128x128 tile] = A[M,K] * Wt[N,K]^T, bf16 in, BK=64.
// XOR-swizzled LDS (R3: conflicts 8.4M -> 0). EPI: 1 = bf16 store,
// 2 = fp32 atomicAdd (split-K). [kb,ke) = K range.
// ---------------------------------------------------------------------------
template <int EPI, typename CT>
__device__ __forceinline__ void gemm_body(const bf16_t* __restrict__ A,
                                          const bf16_t* __restrict__ Wt,
                                          CT* __restrict__ C,
                                          int bm, int bn, int ldc,
                                          int kb, int ke) {
    __shared__ bf16_t As[128 * 64];   // 16 KB
    __shared__ bf16_t Bs[128 * 64];   // 16 KB

    const int tid  = threadIdx.x;
    const int wave = tid >> 6;
    const int lane = tid & 63;
    const int l16  = lane & 15;
    const int quad = lane >> 4;
    const int wm   = (wave >> 1) * 64;
    const int wn   = (wave & 1) * 64;

    f32x4 acc[4][4];
#pragma unroll
    for (int i = 0; i < 4; ++i)
#pragma unroll
        for (int j = 0; j < 4; ++j) acc[i][j] = (f32x4)0.0f;

    // Staging: LDS chunk c = i*256 + tid, row = c>>3, slot jl = c&7;
    // global chunk j_g = jl ^ (row&7)  (swizzle within the 128B row segment).
    const int srow = tid >> 3;                       // 0..31
    const int jg   = (tid & 7) ^ (srow & 7);
    const bf16_t* gA = A  + (size_t)(bm + srow) * kK + jg * 8;
    const bf16_t* gB = Wt + (size_t)(bn + srow) * kK + jg * 8;

    for (int k0 = kb; k0 < ke; k0 += 64) {
#pragma unroll
        for (int i = 0; i < 4; ++i) {
            __builtin_amdgcn_global_load_lds(
                (const __attribute__((address_space(1))) void*)(gA + (size_t)i * 32 * kK + k0),
                (__attribute__((address_space(3))) void*)(As + i * 2048 + wave * 512),
                16, 0, 0);
            __builtin_amdgcn_global_load_lds(
                (const __attribute__((address_space(1))) void*)(gB + (size_t)i * 32 * kK + k0),
                (__attribute__((address_space(3))) void*)(Bs + i * 2048 + wave * 512),
                16, 0, 0);
        }
        __syncthreads();

#pragma unroll
        for (int ph = 0; ph < 2; ++ph) {
            bf16x8 af[4], bfr[4];
#pragma unroll
            for (int i = 0; i < 4; ++i) {
                const int jla = (ph * 4 + quad) ^ (l16 & 7);   // swizzled slot
                af[i]  = *reinterpret_cast<const bf16x8*>(
                    &As[(wm + i * 16 + l16) * 64 + jla * 8]);
                bfr[i] = *reinterpret_cast<const bf16x8*>(
                    &Bs[(wn + i * 16 + l16) * 64 + jla * 8]);
            }
#pragma unroll
            for (int i = 0; i < 4; ++i)
#pragma unroll
                for (int j = 0; j < 4; ++j)
                    acc[i][j] = __builtin_amdgcn_mfma_f32_16x16x32_bf16(
                        af[i], bfr[j], acc[i][j], 0, 0, 0);
        }
        __syncthreads();
    }

    // Epilogue. C/D layout: col = lane&15, row = quad*4 + reg  [m89]
#pragma unroll
    for (int i = 0; i < 4; ++i) {
#pragma unroll
        for (int rr = 0; rr < 4; ++rr) {
            const int row = bm + wm + i * 16 + quad * 4 + rr;
#pragma unroll
            for (int j = 0; j < 4; ++j) {
                const int col = bn + wn + j * 16 + l16;
                if constexpr (EPI == 1) {
                    C[(size_t)row * ldc + col] = __float2bfloat16(acc[i][j][rr]);
                } else {
                    atomicAdd((float*)&C[(size_t)row * ldc + col], acc[i][j][rr]);
                }
            }
        }
    }
}

// ---------------------------------------------------------------------------
// Fused projection kernel: blocks 0..2047 compute kv = chars @ [wk|wv]^T
// (interleaved kvb[8192][4096]: cols 0..2047 = k, 2048.. = v);
// blocks 2048..2175 compute q = x @ wq^T.
// ---------------------------------------------------------------------------
__global__ __launch_bounds__(256, 3) void proj_kernel(
    const bf16_t* __restrict__ xb, const bf16_t* __restrict__ cb,
    const bf16_t* __restrict__ wqb, const bf16_t* __restrict__ wkvb,
    bf16_t* __restrict__ qb, bf16_t* __restrict__ kvb) {
    const int bid = blockIdx.x;
    if (bid < 2048) {
        const int bm = (bid >> 5) * 128;
        const int bn = (bid & 31) * 128;
        gemm_body<1>(cb, wkvb, kvb, bm, bn, 4096, 0, kK);
    } else {
        const int t  = bid - 2048;
        const int bm = (t >> 4) * 128;
        const int bn = (t & 15) * 128;
        gemm_body<1>(xb, wqb, qb, bm, bn, 2048, 0, kK);
    }
}

// Output projection: out[1024,2048] = attn_out @ wo^T, split-K=2 w/ atomics
// (d_out is zeroed by hipMemsetAsync before this launch).
__global__ __launch_bounds__(256, 3) void out_gemm(
    const bf16_t* __restrict__ ob, const bf16_t* __restrict__ wob,
    float* __restrict__ out) {
    const int ks = blockIdx.x >> 7;            // 0/1 K-half
    const int t  = blockIdx.x & 127;
    const int bm = (t >> 4) * 128;
    const int bn = (t & 15) * 128;
    gemm_body<2>(ob, wob, out, bm, bn, 2048, ks * 1024, ks * 1024 + 1024);
}

// ---------------------------------------------------------------------------
// Sliding-window attention. Block = 16 waves; wave w handles query t0+w of
// head h. 184 k/v rows staged once per block (padded stride 72 -> b128 reads
// are bank-uniform). RoPE skipped (exact cancellation). Zero-padded keys give
// score exactly 0 (exp(0) in denominator) and v=0, matching reference.
// R4: PV vectorized — lane=(kg,dg) reads 8 x b128 (8 keys x 8 dims), then
// 3-step shfl_xor reduction over kg; lanes 0..7 store uint4 of 8 bf16.
// ---------------------------------------------------------------------------
static constexpr int kTT   = 16;
static constexpr int kSRC  = kTT + kW - 1;    // 23 source times
static constexpr int kROWS = kSRC * kCV;      // 184 staged rows
static constexpr int kLDK  = 72;              // padded row stride (bf16)

__global__ __launch_bounds__(1024) void attn_kernel(
    const bf16_t* __restrict__ qb,    // [T, 2048]
    const bf16_t* __restrict__ kvb,   // [T*CV, 4096]: [:,0:2048]=k [:,2048:]=v
    bf16_t* __restrict__ ob) {        // [T, 2048]
    __shared__ unsigned short kl[kROWS * kLDK];   // 25.9 KB
    __shared__ unsigned short vl[kROWS * kLDK];   // 25.9 KB
    __shared__ float ql[kTT * 64];                // 4 KB
    __shared__ float al[kTT * 64];                // 4 KB

    const int t0   = blockIdx.x * kTT;
    const int h    = blockIdx.y;
    const int tid  = threadIdx.x;
    const int wave = tid >> 6;
    const int lane = tid & 63;

    ql[tid] = __bfloat162float(qb[(size_t)(t0 + wave) * kDim + h * kHD + lane]);

    const long long grow0 = (long long)(t0 - (kW - 1)) * kCV;
    for (int c = tid; c < kROWS * 8; c += 1024) {
        const int r   = c >> 3;
        const int sub = c & 7;
        const long long grow = grow0 + r;
        uint4 kd = make_uint4(0, 0, 0, 0), vd = make_uint4(0, 0, 0, 0);
        if (grow >= 0) {
            const size_t gb = (size_t)grow * 4096 + h * kHD + sub * 8;
            kd = *reinterpret_cast<const uint4*>(kvb + gb);
            vd = *reinterpret_cast<const uint4*>(kvb + gb + 2048);
        }
        *reinterpret_cast<uint4*>(&kl[r * kLDK + sub * 8]) = kd;
        *reinterpret_cast<uint4*>(&vl[r * kLDK + sub * 8]) = vd;
    }
    __syncthreads();

    // ---- Scores: lane = key kk -> staged row wave*8 + kk.
    const int r = wave * kCV + lane;
    float s = 0.0f;
#pragma unroll
    for (int c = 0; c < 8; ++c) {
        union { uint4 u; unsigned short us[8]; } kv;
        kv.u = *reinterpret_cast<const uint4*>(&kl[r * kLDK + c * 8]);
        const float4 qa = *reinterpret_cast<const float4*>(&ql[wave * 64 + c * 8]);
        const float4 qc = *reinterpret_cast<const float4*>(&ql[wave * 64 + c * 8 + 4]);
        s += bf_bits_to_f32(kv.us[0]) * qa.x + bf_bits_to_f32(kv.us[1]) * qa.y +
             bf_bits_to_f32(kv.us[2]) * qa.z + bf_bits_to_f32(kv.us[3]) * qa.w +
             bf_bits_to_f32(kv.us[4]) * qc.x + bf_bits_to_f32(kv.us[5]) * qc.y +
             bf_bits_to_f32(kv.us[6]) * qc.z + bf_bits_to_f32(kv.us[7]) * qc.w;
    }
    s *= 0.125f;

    float m = s;
#pragma unroll
    for (int off = 32; off; off >>= 1) m = fmaxf(m, __shfl_xor(m, off));
    const float e = __expf(s - m);
    float sum = e;
#pragma unroll
    for (int off = 32; off; off >>= 1) sum += __shfl_xor(sum, off);
    al[wave * 64 + lane] = e / sum;   // same-wave producer/consumer

    // ---- PV, vectorized. lane = (kg = lane>>3, dg = lane&7).
    const int kg = lane >> 3;
    const int dg = lane & 7;
    float acc8[8];
#pragma unroll
    for (int i = 0; i < 8; ++i) acc8[i] = 0.0f;
#pragma unroll
    for (int j = 0; j < 8; ++j) {
        const int key = kg * 8 + j;
        const int rr  = wave * kCV + key;          // staged row for this key
        union { uint4 u; unsigned short us[8]; } vv;
        vv.u = *reinterpret_cast<const uint4*>(&vl[rr * kLDK + dg * 8]);
        const float p = al[wave * 64 + key];       // broadcast (same addr x8)
#pragma unroll
        for (int i = 0; i < 8; ++i) acc8[i] += p * bf_bits_to_f32(vv.us[i]);
    }
    // Reduce over kg (lane bits 3..5).
#pragma unroll
    for (int off = 8; off <= 32; off <<= 1)
#pragma unroll
        for (int i = 0; i < 8; ++i) acc8[i] += __shfl_xor(acc8[i], off);

    if (kg == 0) {
        union { bf16_t hh[8]; uint4 u; } o;
#pragma unroll
        for (int i = 0; i < 8; ++i) o.hh[i] = __float2bfloat16(acc8[i]);
        *reinterpret_cast<uint4*>(
            &ob[(size_t)(t0 + wave) * kDim + h * kHD + dg * 8]) = o.u;
    }
}

// ---------------------------------------------------------------------------
extern "C" void kernel_launch(void* const* d_in, const int* in_sizes, int n_in,
                              void* d_out, int out_size, void* d_ws,
                              size_t ws_size, hipStream_t stream) {
    const float* x     = (const float*)d_in[0];
    const float* chars = (const float*)d_in[1];
    const float* wq    = (const float*)d_in[2];
    const float* wk    = (const float*)d_in[3];
    const float* wv    = (const float*)d_in[4];
    const float* wo    = (const float*)d_in[5];
    float* out = (float*)d_out;

    // Workspace carve-up (~132 MiB total).
    char* p = (char*)d_ws;
    bf16_t* xb   = (bf16_t*)p; p += (size_t)kT * kDim * 2;            // 4 MB
    bf16_t* cb   = (bf16_t*)p; p += (size_t)kT * kCV * kDim * 2;      // 32 MB
    bf16_t* wqb  = (bf16_t*)p; p += (size_t)kDim * kDim * 2;          // 8 MB
    bf16_t* wkvb = (bf16_t*)p; p += (size_t)2 * kDim * kDim * 2;      // 16 MB
    bf16_t* wob  = (bf16_t*)p; p += (size_t)kDim * kDim * 2;          // 8 MB
    bf16_t* qb   = (bf16_t*)p; p += (size_t)kT * kDim * 2;            // 4 MB
    bf16_t* kvb  = (bf16_t*)p; p += (size_t)kT * kCV * 2 * kDim * 2;  // 64 MB
    bf16_t* ob   = (bf16_t*)p; p += (size_t)kT * kDim * 2;            // 4 MB

    // One cast launch for all six tensors.
    CastArgs ca;
    ca.src[0] = x;     ca.dst[0] = xb;
    ca.src[1] = chars; ca.dst[1] = cb;
    ca.src[2] = wq;    ca.dst[2] = wqb;
    ca.src[3] = wk;    ca.dst[3] = wkvb;
    ca.src[4] = wv;    ca.dst[4] = wkvb + (size_t)kDim * kDim;
    ca.src[5] = wo;    ca.dst[5] = wob;
    const int sizes[6] = {kT * kDim, kT * kCV * kDim, kDim * kDim,
                          kDim * kDim, kDim * kDim, kDim * kDim};
    int cum = 0;
    ca.cum[0] = 0;
    for (int i = 0; i < 6; ++i) { cum += sizes[i] / 8; ca.cum[i + 1] = cum; }
    cast_all<<<dim3((cum + 255) / 256), dim3(256), 0, stream>>>(ca, cum);

    // Zero d_out for the split-K atomic epilogue.
    hipMemsetAsync(out, 0, (size_t)kT * kDim * sizeof(float), stream);

    // Fused k|v (N=4096) + q projections: 2048 + 128 blocks, one launch.
    proj_kernel<<<dim3(2176), dim3(256), 0, stream>>>(xb, cb, wqb, wkvb, qb, kvb);

    // Sliding-window attention.
    attn_kernel<<<dim3(kT / kTT, kNH), dim3(1024), 0, stream>>>(qb, kvb, ob);

    // Output projection, split-K=2 with fp32 atomics.
    out_gemm<<<dim3(256), dim3(256), 0, stream>>>(ob, wob, out);
}

// Round 5
// 365.223 us; speedup vs baseline: 1.0023x; 1.0023x over previous
//
#include <hip/hip_runtime.h>
#include <hip/hip_bf16.h>
#include <cstdint>
#include <cstddef>

// Problem constants (B=1 implicit)
static constexpr int kT   = 1024;
static constexpr int kCV  = 8;
static constexpr int kDim = 2048;
static constexpr int kNH  = 32;
static constexpr int kHD  = 64;
static constexpr int kW   = 8;
static constexpr int kK   = 2048;   // inner dim of every GEMM

using bf16_t = __hip_bfloat16;

typedef __attribute__((ext_vector_type(8))) __bf16 bf16x8;
typedef __attribute__((ext_vector_type(4))) float  f32x4;

__device__ __forceinline__ float bf_bits_to_f32(unsigned short u) {
    union { unsigned int i; float f; } c;
    c.i = ((unsigned int)u) << 16;
    return c.f;
}

// ---------------------------------------------------------------------------
// Merged fp32 -> bf16 cast for all 6 inputs in ONE launch.
// ---------------------------------------------------------------------------
struct CastArgs {
    const float* src[6];
    bf16_t*      dst[6];
    int          cum[7];   // cumulative 8-elem chunk counts
};

__global__ void cast_all(CastArgs a, int total_chunks) {
    const int c = blockIdx.x * blockDim.x + threadIdx.x;
    if (c >= total_chunks) return;
    int r = 0;
#pragma unroll
    for (int i = 1; i <= 5; ++i) r += (c >= a.cum[i]) ? 1 : 0;
    const int local = c - a.cum[r];
    const float* s = a.src[r] + (size_t)local * 8;
    bf16_t*      d = a.dst[r] + (size_t)local * 8;
    const float4 lo = *reinterpret_cast<const float4*>(s);
    const float4 hi = *reinterpret_cast<const float4*>(s + 4);
    union { bf16_t h[8]; uint4 u; } o;
    o.h[0] = __float2bfloat16(lo.x); o.h[1] = __float2bfloat16(lo.y);
    o.h[2] = __float2bfloat16(lo.z); o.h[3] = __float2bfloat16(lo.w);
    o.h[4] = __float2bfloat16(hi.x); o.h[5] = __float2bfloat16(hi.y);
    o.h[6] = __float2bfloat16(hi.z); o.h[7] = __float2bfloat16(hi.w);
    *reinterpret_cast<uint4*>(d) = o.u;
}

// ---------------------------------------------------------------------------
// GEMM body: C[128x128 tile] = A[M,K] * Wt[N,K]^T, bf16 in, BK=64.
// XOR-swizzled LDS (R3: conflicts 8.4M -> 0).
// ---------------------------------------------------------------------------
template <bool OUT_BF16, typename CT>
__device__ __forceinline__ void gemm_body(const bf16_t* __restrict__ A,
                                          const bf16_t* __restrict__ Wt,
                                          CT* __restrict__ C,
                                          int bm, int bn, int ldc) {
    __shared__ bf16_t As[128 * 64];   // 16 KB
    __shared__ bf16_t Bs[128 * 64];   // 16 KB

    const int tid  = threadIdx.x;
    const int wave = tid >> 6;
    const int lane = tid & 63;
    const int l16  = lane & 15;
    const int quad = lane >> 4;
    const int wm   = (wave >> 1) * 64;
    const int wn   = (wave & 1) * 64;

    f32x4 acc[4][4];
#pragma unroll
    for (int i = 0; i < 4; ++i)
#pragma unroll
        for (int j = 0; j < 4; ++j) acc[i][j] = (f32x4)0.0f;

    // Staging: LDS chunk c = i*256 + tid, row = c>>3, slot jl = c&7;
    // global chunk j_g = jl ^ (row&7)  (swizzle within the 128B row segment).
    const int srow = tid >> 3;                       // 0..31
    const int jg   = (tid & 7) ^ (srow & 7);
    const bf16_t* gA = A  + (size_t)(bm + srow) * kK + jg * 8;
    const bf16_t* gB = Wt + (size_t)(bn + srow) * kK + jg * 8;

    for (int k0 = 0; k0 < kK; k0 += 64) {
#pragma unroll
        for (int i = 0; i < 4; ++i) {
            __builtin_amdgcn_global_load_lds(
                (const __attribute__((address_space(1))) void*)(gA + (size_t)i * 32 * kK + k0),
                (__attribute__((address_space(3))) void*)(As + i * 2048 + wave * 512),
                16, 0, 0);
            __builtin_amdgcn_global_load_lds(
                (const __attribute__((address_space(1))) void*)(gB + (size_t)i * 32 * kK + k0),
                (__attribute__((address_space(3))) void*)(Bs + i * 2048 + wave * 512),
                16, 0, 0);
        }
        __syncthreads();

#pragma unroll
        for (int ph = 0; ph < 2; ++ph) {
            bf16x8 af[4], bfr[4];
#pragma unroll
            for (int i = 0; i < 4; ++i) {
                const int jla = (ph * 4 + quad) ^ (l16 & 7);   // swizzled slot
                af[i]  = *reinterpret_cast<const bf16x8*>(
                    &As[(wm + i * 16 + l16) * 64 + jla * 8]);
                bfr[i] = *reinterpret_cast<const bf16x8*>(
                    &Bs[(wn + i * 16 + l16) * 64 + jla * 8]);
            }
#pragma unroll
            for (int i = 0; i < 4; ++i)
#pragma unroll
                for (int j = 0; j < 4; ++j)
                    acc[i][j] = __builtin_amdgcn_mfma_f32_16x16x32_bf16(
                        af[i], bfr[j], acc[i][j], 0, 0, 0);
        }
        __syncthreads();
    }

    // Epilogue. C/D layout: col = lane&15, row = quad*4 + reg  [m89]
#pragma unroll
    for (int i = 0; i < 4; ++i) {
#pragma unroll
        for (int rr = 0; rr < 4; ++rr) {
            const int row = bm + wm + i * 16 + quad * 4 + rr;
#pragma unroll
            for (int j = 0; j < 4; ++j) {
                const int col = bn + wn + j * 16 + l16;
                if constexpr (OUT_BF16) {
                    C[(size_t)row * ldc + col] = __float2bfloat16(acc[i][j][rr]);
                } else {
                    C[(size_t)row * ldc + col] = acc[i][j][rr];
                }
            }
        }
    }
}

// ---------------------------------------------------------------------------
// Fused projection kernel: blocks 0..2047 compute kv = chars @ [wk|wv]^T
// (interleaved kvb[8192][4096]: cols 0..2047 = k, 2048.. = v);
// blocks 2048..2175 compute q = x @ wq^T.
// ---------------------------------------------------------------------------
__global__ __launch_bounds__(256, 3) void proj_kernel(
    const bf16_t* __restrict__ xb, const bf16_t* __restrict__ cb,
    const bf16_t* __restrict__ wqb, const bf16_t* __restrict__ wkvb,
    bf16_t* __restrict__ qb, bf16_t* __restrict__ kvb) {
    const int bid = blockIdx.x;
    if (bid < 2048) {
        const int bm = (bid >> 5) * 128;
        const int bn = (bid & 31) * 128;
        gemm_body<true>(cb, wkvb, kvb, bm, bn, 4096);
    } else {
        const int t  = bid - 2048;
        const int bm = (t >> 4) * 128;
        const int bn = (t & 15) * 128;
        gemm_body<true>(xb, wqb, qb, bm, bn, 2048);
    }
}

// Output projection: out[1024,2048] = attn_out @ wo^T (fp32 out, no split-K —
// R4's atomic split-K was neutral/negative, reverted).
__global__ __launch_bounds__(256, 3) void out_gemm(
    const bf16_t* __restrict__ ob, const bf16_t* __restrict__ wob,
    float* __restrict__ out) {
    const int bm = (blockIdx.x >> 4) * 128;
    const int bn = (blockIdx.x & 15) * 128;
    gemm_body<false>(ob, wob, out, bm, bn, 2048);
}

// ---------------------------------------------------------------------------
// Sliding-window attention, R5: ONE WAVE PER (t, head); NO LDS, NO BARRIERS.
// Lane = (kg, dg): kg = window index w (key = w*8 + c, c = 0..7), dg = dim
// octet. Each lane loads its 8 k-rows and 8 v-rows (consecutive rows
// st*8..st*8+7 at dim slice dg*8) directly global->VGPR as uint4, computes
// partial dot products, and all reductions are shfl_xor butterflies:
//   dg-reduce (1,2,4)  -> full scores s[8] per lane
//   kg-reduce (8,16,32)-> softmax max & sum over all 64 keys
//   kg-reduce (8,16,32)-> PV output octet
// RoPE skipped (exact cancellation: freqs[t] broadcast over window keys).
// st < 0 lanes load zeros -> score exactly 0 (in softmax denom), v = 0,
// matching the reference's zero-pad semantics.
// ---------------------------------------------------------------------------
__global__ __launch_bounds__(256) void attn_kernel(
    const bf16_t* __restrict__ qb,    // [T, 2048]
    const bf16_t* __restrict__ kvb,   // [T*CV, 4096]: [:,0:2048]=k [:,2048:]=v
    bf16_t* __restrict__ ob) {        // [T, 2048]
    const int wid  = (blockIdx.x * 256 + threadIdx.x) >> 6;  // 0..32767
    const int t    = wid >> 5;
    const int h    = wid & 31;
    const int lane = threadIdx.x & 63;
    const int kg   = lane >> 3;   // window index w
    const int dg   = lane & 7;    // dim octet

    const int  st    = t - (kW - 1) + kg;   // source time for this lane
    const bool valid = (st >= 0);

    // q slice (8 lanes per dg share the address -> broadcast).
    union { uint4 u; unsigned short us[8]; } qu;
    qu.u = *reinterpret_cast<const uint4*>(qb + (size_t)t * kDim + h * kHD + dg * 8);
    float qf[8];
#pragma unroll
    for (int i = 0; i < 8; ++i) qf[i] = bf_bits_to_f32(qu.us[i]);

    // Load 8 k-rows and 8 v-rows for window kg (rows st*8 .. st*8+7).
    const size_t base =
        (size_t)(valid ? st : 0) * (size_t)(kCV * 4096) + h * kHD + dg * 8;
    union { uint4 u; unsigned short us[8]; } kr[8], vr[8];
#pragma unroll
    for (int j = 0; j < 8; ++j) {
        const size_t a = base + (size_t)j * 4096;
        kr[j].u = valid ? *reinterpret_cast<const uint4*>(kvb + a)
                        : make_uint4(0, 0, 0, 0);
        vr[j].u = valid ? *reinterpret_cast<const uint4*>(kvb + a + 2048)
                        : make_uint4(0, 0, 0, 0);
    }

    // Partial scores over this lane's dim octet, then dg-butterfly.
    float s[8];
#pragma unroll
    for (int j = 0; j < 8; ++j) {
        float acc = 0.0f;
#pragma unroll
        for (int i = 0; i < 8; ++i) acc += qf[i] * bf_bits_to_f32(kr[j].us[i]);
        s[j] = acc;
    }
#pragma unroll
    for (int off = 1; off <= 4; off <<= 1)
#pragma unroll
        for (int j = 0; j < 8; ++j) s[j] += __shfl_xor(s[j], off);
#pragma unroll
    for (int j = 0; j < 8; ++j) s[j] *= 0.125f;   // 1/sqrt(64)

    // Softmax over all 64 keys (8 local + kg-butterfly).
    float m = s[0];
#pragma unroll
    for (int j = 1; j < 8; ++j) m = fmaxf(m, s[j]);
#pragma unroll
    for (int off = 8; off <= 32; off <<= 1) m = fmaxf(m, __shfl_xor(m, off));
    float e[8], sum = 0.0f;
#pragma unroll
    for (int j = 0; j < 8; ++j) { e[j] = __expf(s[j] - m); sum += e[j]; }
#pragma unroll
    for (int off = 8; off <= 32; off <<= 1) sum += __shfl_xor(sum, off);
    const float inv = 1.0f / sum;

    // PV: this lane's 8 keys x its dim octet, then kg-butterfly.
    float o[8];
#pragma unroll
    for (int i = 0; i < 8; ++i) o[i] = 0.0f;
#pragma unroll
    for (int j = 0; j < 8; ++j) {
        const float p = e[j] * inv;
#pragma unroll
        for (int i = 0; i < 8; ++i) o[i] += p * bf_bits_to_f32(vr[j].us[i]);
    }
#pragma unroll
    for (int off = 8; off <= 32; off <<= 1)
#pragma unroll
        for (int i = 0; i < 8; ++i) o[i] += __shfl_xor(o[i], off);

    if (kg == 0) {   // lanes 0..7 store one contiguous 128B row segment
        union { bf16_t hh[8]; uint4 u; } ov;
#pragma unroll
        for (int i = 0; i < 8; ++i) ov.hh[i] = __float2bfloat16(o[i]);
        *reinterpret_cast<uint4*>(&ob[(size_t)t * kDim + h * kHD + dg * 8]) = ov.u;
    }
}

// ---------------------------------------------------------------------------
extern "C" void kernel_launch(void* const* d_in, const int* in_sizes, int n_in,
                              void* d_out, int out_size, void* d_ws,
                              size_t ws_size, hipStream_t stream) {
    const float* x     = (const float*)d_in[0];
    const float* chars = (const float*)d_in[1];
    const float* wq    = (const float*)d_in[2];
    const float* wk    = (const float*)d_in[3];
    const float* wv    = (const float*)d_in[4];
    const float* wo    = (const float*)d_in[5];
    float* out = (float*)d_out;

    // Workspace carve-up (~132 MiB total).
    char* p = (char*)d_ws;
    bf16_t* xb   = (bf16_t*)p; p += (size_t)kT * kDim * 2;            // 4 MB
    bf16_t* cb   = (bf16_t*)p; p += (size_t)kT * kCV * kDim * 2;      // 32 MB
    bf16_t* wqb  = (bf16_t*)p; p += (size_t)kDim * kDim * 2;          // 8 MB
    bf16_t* wkvb = (bf16_t*)p; p += (size_t)2 * kDim * kDim * 2;      // 16 MB
    bf16_t* wob  = (bf16_t*)p; p += (size_t)kDim * kDim * 2;          // 8 MB
    bf16_t* qb   = (bf16_t*)p; p += (size_t)kT * kDim * 2;            // 4 MB
    bf16_t* kvb  = (bf16_t*)p; p += (size_t)kT * kCV * 2 * kDim * 2;  // 64 MB
    bf16_t* ob   = (bf16_t*)p; p += (size_t)kT * kDim * 2;            // 4 MB

    // One cast launch for all six tensors.
    CastArgs ca;
    ca.src[0] = x;     ca.dst[0] = xb;
    ca.src[1] = chars; ca.dst[1] = cb;
    ca.src[2] = wq;    ca.dst[2] = wqb;
    ca.src[3] = wk;    ca.dst[3] = wkvb;
    ca.src[4] = wv;    ca.dst[4] = wkvb + (size_t)kDim * kDim;
    ca.src[5] = wo;    ca.dst[5] = wob;
    const int sizes[6] = {kT * kDim, kT * kCV * kDim, kDim * kDim,
                          kDim * kDim, kDim * kDim, kDim * kDim};
    int cum = 0;
    ca.cum[0] = 0;
    for (int i = 0; i < 6; ++i) { cum += sizes[i] / 8; ca.cum[i + 1] = cum; }
    cast_all<<<dim3((cum + 255) / 256), dim3(256), 0, stream>>>(ca, cum);

    // Fused k|v (N=4096) + q projections: 2048 + 128 blocks, one launch.
    proj_kernel<<<dim3(2176), dim3(256), 0, stream>>>(xb, cb, wqb, wkvb, qb, kvb);

    // Sliding-window attention: 32768 waves (1 per (t,h)), 4 waves/block.
    attn_kernel<<<dim3(kT * kNH / 4), dim3(256), 0, stream>>>(qb, kvb, ob);

    // Output projection (fp32 out).
    out_gemm<<<dim3(128), dim3(256), 0, stream>>>(ob, wob, out);
}